// Round 1
// baseline (667.850 us; speedup 1.0000x reference)
//
#include <hip/hip_runtime.h>

#define B_ 1024
#define T_ 200
#define H_ 128

typedef __attribute__((ext_vector_type(8))) short short8;
typedef __attribute__((ext_vector_type(4))) float f32x4;

#define MFMA(a, b, c) __builtin_amdgcn_mfma_f32_16x16x32_bf16((a), (b), (c), 0, 0, 0)

static __device__ __forceinline__ short f2bf(float f) {
  unsigned u = __float_as_uint(f);
  u += 0x7fffu + ((u >> 16) & 1u);   // RNE
  return (short)(u >> 16);
}
static __device__ __forceinline__ float bf2f(short s) {
  return __uint_as_float(((unsigned)(unsigned short)s) << 16);
}
static __device__ __forceinline__ float sigmoid_f(float x) {
  return 1.0f / (1.0f + __expf(-x));
}
static __device__ __forceinline__ float tanh_f(float x) {
  float e = __expf(2.0f * x);
  return 1.0f - 2.0f / (e + 1.0f);
}

// ---------------------------------------------------------------------------
// K1: attention scores (split-bf16 MFMA, fp32-grade accuracy) + fused softmax.
// One block per batch b. 4 waves; wave w owns h-coltiles {2w, 2w+1}.
// ---------------------------------------------------------------------------
__global__ __launch_bounds__(256, 1) void scores_softmax_kernel(
    const float* __restrict__ tgt, const float* __restrict__ hist,
    const float* __restrict__ Ww, const float* __restrict__ Wb,
    float* __restrict__ att) {
  const int b = blockIdx.x;
  const int tid = threadIdx.x;
  const int lane = tid & 63;
  const int wave = tid >> 6;
  const int n = lane & 15;
  const int quad = lane >> 4;

  __shared__ short ta_hi[16 * 128];   // targets tile, bf16 hi, XOR-swizzled A-layout
  __shared__ short ta_lo[16 * 128];   // bf16 residual
  __shared__ float hi_f[16 * 132];    // history tile fp32, padded rows (bank spread)
  __shared__ float sp[16 * 8];        // per-(t,coltile) partial dot
  __shared__ float s_lds[200];
  __shared__ float red[8];

  // Register-resident W_w B-fragments (hi/lo split)
  short8 whi[2][4], wlo[2][4];
  float wb[2];
#pragma unroll
  for (int c = 0; c < 2; ++c) {
    const int row = (2 * wave + c) * 16 + n;
    wb[c] = Wb[row];
#pragma unroll
    for (int ks = 0; ks < 4; ++ks) {
      const float* p = Ww + row * H_ + ks * 32 + quad * 8;
#pragma unroll
      for (int j = 0; j < 8; ++j) {
        float f = p[j];
        short h16 = f2bf(f);
        whi[c][ks][j] = h16;
        wlo[c][ks][j] = f2bf(f - bf2f(h16));
      }
    }
  }

  const int sm = tid >> 4, sc = tid & 15;
  const int cpos = sc ^ (sm & 7);

  for (int mt = 0; mt < 13; ++mt) {
    const int tt = mt * 16 + sm;
    float4 v0 = make_float4(0, 0, 0, 0), v1 = make_float4(0, 0, 0, 0);
    float4 h0 = make_float4(0, 0, 0, 0), h1 = make_float4(0, 0, 0, 0);
    if (tt < T_) {
      const float* p = tgt + (b * T_ + tt) * H_ + sc * 8;
      v0 = *(const float4*)p;
      v1 = *(const float4*)(p + 4);
      const float* q = hist + (b * T_ + tt) * H_ + sc * 8;
      h0 = *(const float4*)q;
      h1 = *(const float4*)(q + 4);
    }
    *(float4*)&hi_f[sm * 132 + sc * 8] = h0;
    *(float4*)&hi_f[sm * 132 + sc * 8 + 4] = h1;
    {
      float fv[8] = {v0.x, v0.y, v0.z, v0.w, v1.x, v1.y, v1.z, v1.w};
      short8 hv, lv;
#pragma unroll
      for (int j = 0; j < 8; ++j) {
        short h16 = f2bf(fv[j]);
        hv[j] = h16;
        lv[j] = f2bf(fv[j] - bf2f(h16));
      }
      *(short8*)&ta_hi[sm * 128 + cpos * 8] = hv;
      *(short8*)&ta_lo[sm * 128 + cpos * 8] = lv;
    }
    __syncthreads();

    // aw = tgt @ Ww^T via 3-pass split bf16: hi*hi + hi*lo + lo*hi
    f32x4 acc0 = {0, 0, 0, 0}, acc1 = {0, 0, 0, 0};
#pragma unroll
    for (int ks = 0; ks < 4; ++ks) {
      const int cp = ((ks * 4 + quad) ^ (n & 7)) * 8 + n * 128;
      short8 ahi = *(short8*)&ta_hi[cp];
      short8 alo = *(short8*)&ta_lo[cp];
      acc0 = MFMA(ahi, whi[0][ks], acc0);
      acc0 = MFMA(ahi, wlo[0][ks], acc0);
      acc0 = MFMA(alo, whi[0][ks], acc0);
      acc1 = MFMA(ahi, whi[1][ks], acc1);
      acc1 = MFMA(ahi, wlo[1][ks], acc1);
      acc1 = MFMA(alo, whi[1][ks], acc1);
    }
    // s partials: (aw + Wb) .* hist, reduce over the 16 columns of each coltile
#pragma unroll
    for (int c = 0; c < 2; ++c) {
      f32x4 a = c ? acc1 : acc0;
      const int hcol = (2 * wave + c) * 16 + n;
#pragma unroll
      for (int r = 0; r < 4; ++r) {
        const int m = quad * 4 + r;
        float v = (a[r] + wb[c]) * hi_f[m * 132 + hcol];
        v += __shfl_xor(v, 1);
        v += __shfl_xor(v, 2);
        v += __shfl_xor(v, 4);
        v += __shfl_xor(v, 8);
        if (n == 0) sp[m * 8 + 2 * wave + c] = v;
      }
    }
    __syncthreads();
    if (tid < 16) {
      float s = 0.0f;
#pragma unroll
      for (int c = 0; c < 8; ++c) s += sp[tid * 8 + c];
      const int t2 = mt * 16 + tid;
      if (t2 < T_) s_lds[t2] = s;
    }
    __syncthreads();
  }

  // fp32 softmax over time
  float v = (tid < T_) ? s_lds[tid] : -3.0e38f;
  float mx = v;
#pragma unroll
  for (int d = 1; d < 64; d <<= 1) mx = fmaxf(mx, __shfl_xor(mx, d));
  if (lane == 0) red[wave] = mx;
  __syncthreads();
  mx = fmaxf(fmaxf(red[0], red[1]), fmaxf(red[2], red[3]));
  float e = (tid < T_) ? __expf(v - mx) : 0.0f;
  float sm2 = e;
#pragma unroll
  for (int d = 1; d < 64; d <<= 1) sm2 += __shfl_xor(sm2, d);
  if (lane == 0) red[4 + wave] = sm2;
  __syncthreads();
  sm2 = red[4] + red[5] + red[6] + red[7];
  if (tid < T_) att[b * T_ + tid] = e / sm2;
}

// ---------------------------------------------------------------------------
// K3: fused recurrent scan. 64 blocks x 16 batch rows; 200 sequential steps.
// All 6 weight matrices as register-resident bf16 B-frags; h double-buffered
// in XOR-swizzled LDS; x-row global loads pipelined one full step ahead.
// One __syncthreads per step.
// ---------------------------------------------------------------------------
__global__ __launch_bounds__(256, 1) void scan_kernel(
    const float* __restrict__ hist,
    const float* __restrict__ xu_w, const float* __restrict__ xu_b,
    const float* __restrict__ hu_w, const float* __restrict__ hu_b,
    const float* __restrict__ xr_w, const float* __restrict__ xr_b,
    const float* __restrict__ hr_w, const float* __restrict__ hr_b,
    const float* __restrict__ xg_w, const float* __restrict__ xg_b,
    const float* __restrict__ hg_w, const float* __restrict__ hg_b,
    const float* __restrict__ att, float* __restrict__ h_out) {
  const int tid = threadIdx.x;
  const int lane = tid & 63;
  const int wave = tid >> 6;
  const int n = lane & 15;
  const int quad = lane >> 4;
  const int r0 = blockIdx.x * 16;

  __shared__ short hbuf[2][16 * 128];
  __shared__ short xbuf[2][16 * 128];
  __shared__ float att_l[16 * 200];

  // mats: 0=xu 1=hu 2=xr 3=hr 4=xg 5=hg
  short8 wf[6][2][4];
  {
    const float* Wm[6] = {xu_w, hu_w, xr_w, hr_w, xg_w, hg_w};
#pragma unroll
    for (int M = 0; M < 6; ++M) {
#pragma unroll
      for (int c = 0; c < 2; ++c) {
        const int row = (2 * wave + c) * 16 + n;
#pragma unroll
        for (int ks = 0; ks < 4; ++ks) {
          const float* p = Wm[M] + row * H_ + ks * 32 + quad * 8;
          short8 w;
#pragma unroll
          for (int j = 0; j < 8; ++j) w[j] = f2bf(p[j]);
          wf[M][c][ks] = w;
        }
      }
    }
  }

  float bu[2], br[2], bxg[2], bhg[2];
#pragma unroll
  for (int c = 0; c < 2; ++c) {
    const int o = (2 * wave + c) * 16 + n;
    bu[c] = xu_b[o] + hu_b[o];
    br[c] = xr_b[o] + hr_b[o];
    bxg[c] = xg_b[o];
    bhg[c] = hg_b[o];
  }

  // preload attention rows [16][200] (contiguous in global)
  for (int i = tid; i < 16 * T_; i += 256) att_l[i] = att[r0 * T_ + i];
  // h0 = 0
  for (int i = tid; i < 16 * 128; i += 256) hbuf[0][i] = 0;

  const int sm = tid >> 4, sc = tid & 15;
  const int spos = sm * 128 + (sc ^ (sm & 7)) * 8;
  const float* hrow0 = hist + (r0 + sm) * (T_ * H_) + sc * 8;
  {  // stage x(0)
    float4 a0 = *(const float4*)hrow0;
    float4 a1 = *(const float4*)(hrow0 + 4);
    float fv[8] = {a0.x, a0.y, a0.z, a0.w, a1.x, a1.y, a1.z, a1.w};
    short8 v;
#pragma unroll
    for (int j = 0; j < 8; ++j) v[j] = f2bf(fv[j]);
    *(short8*)&xbuf[0][spos] = v;
  }
  // prefetch x(1)
  float4 xva = *(const float4*)(hrow0 + H_);
  float4 xvb = *(const float4*)(hrow0 + H_ + 4);

  float hreg[2][4];  // fp32 h-state this lane owns (D-layout)
#pragma unroll
  for (int c = 0; c < 2; ++c)
#pragma unroll
    for (int r = 0; r < 4; ++r) hreg[c][r] = 0.0f;

  __syncthreads();

#pragma unroll 2
  for (int t = 0; t < T_; ++t) {
    const int cur = t & 1, nxt = cur ^ 1;
    short8 ha[4], xa[4];
#pragma unroll
    for (int ks = 0; ks < 4; ++ks) {
      const int cp = ((ks * 4 + quad) ^ (n & 7)) * 8 + n * 128;
      ha[ks] = *(short8*)&hbuf[cur][cp];
      xa[ks] = *(short8*)&xbuf[cur][cp];
    }
    f32x4 a_xu = {0, 0, 0, 0}, a_hu = {0, 0, 0, 0}, a_xr = {0, 0, 0, 0},
          a_hr = {0, 0, 0, 0}, a_xg = {0, 0, 0, 0}, a_hg = {0, 0, 0, 0};
    f32x4 b_xu = {0, 0, 0, 0}, b_hu = {0, 0, 0, 0}, b_xr = {0, 0, 0, 0},
          b_hr = {0, 0, 0, 0}, b_xg = {0, 0, 0, 0}, b_hg = {0, 0, 0, 0};
#pragma unroll
    for (int ks = 0; ks < 4; ++ks) {
      a_xu = MFMA(xa[ks], wf[0][0][ks], a_xu);
      b_xu = MFMA(xa[ks], wf[0][1][ks], b_xu);
      a_hu = MFMA(ha[ks], wf[1][0][ks], a_hu);
      b_hu = MFMA(ha[ks], wf[1][1][ks], b_hu);
      a_xr = MFMA(xa[ks], wf[2][0][ks], a_xr);
      b_xr = MFMA(xa[ks], wf[2][1][ks], b_xr);
      a_hr = MFMA(ha[ks], wf[3][0][ks], a_hr);
      b_hr = MFMA(ha[ks], wf[3][1][ks], b_hr);
      a_xg = MFMA(xa[ks], wf[4][0][ks], a_xg);
      b_xg = MFMA(xa[ks], wf[4][1][ks], b_xg);
      a_hg = MFMA(ha[ks], wf[5][0][ks], a_hg);
      b_hg = MFMA(ha[ks], wf[5][1][ks], b_hg);
    }
    // stage x(t+1) (loaded one step ago)
    {
      float fv[8] = {xva.x, xva.y, xva.z, xva.w, xvb.x, xvb.y, xvb.z, xvb.w};
      short8 v;
#pragma unroll
      for (int j = 0; j < 8; ++j) v[j] = f2bf(fv[j]);
      *(short8*)&xbuf[nxt][spos] = v;
    }
    // prefetch x(t+2)
    {
      const int tp = (t + 2 < T_) ? (t + 2) : (T_ - 1);
      const float* p = hrow0 + tp * H_;
      xva = *(const float4*)p;
      xvb = *(const float4*)(p + 4);
    }
    // gates + h update (this lane owns rows m=quad*4+r, cols o)
#pragma unroll
    for (int c = 0; c < 2; ++c) {
      const int o = (2 * wave + c) * 16 + n;
      const int chunkb = o >> 3;
      const int osub = o & 7;
      const f32x4 xu_v = c ? b_xu : a_xu;
      const f32x4 hu_v = c ? b_hu : a_hu;
      const f32x4 xr_v = c ? b_xr : a_xr;
      const f32x4 hr_v = c ? b_hr : a_hr;
      const f32x4 xg_v = c ? b_xg : a_xg;
      const f32x4 hg_v = c ? b_hg : a_hg;
#pragma unroll
      for (int r = 0; r < 4; ++r) {
        const int m = quad * 4 + r;
        const float a_t = att_l[m * T_ + t];
        const float u = sigmoid_f(xu_v[r] + hu_v[r] + bu[c]) * a_t;
        const float rg = sigmoid_f(xr_v[r] + hr_v[r] + br[c]);
        const float g = tanh_f(xg_v[r] + bxg[c] + rg * (hg_v[r] + bhg[c]));
        const float hn = (1.0f - u) * hreg[c][r] + u * g;
        hreg[c][r] = hn;
        hbuf[nxt][m * 128 + ((chunkb ^ (m & 7)) << 3) + osub] = f2bf(hn);
        if (t == T_ - 1) h_out[(r0 + m) * H_ + o] = hn;
      }
    }
    __syncthreads();
  }
}

// ---------------------------------------------------------------------------
// K4: out = [h | targets[:,0]] @ ln2_w^T + ln2_b   (fp32)
// ---------------------------------------------------------------------------
__global__ __launch_bounds__(256, 4) void final_kernel(
    const float* __restrict__ tgt, const float* __restrict__ hfin,
    const float* __restrict__ w, const float* __restrict__ bias,
    float* __restrict__ out) {
  const int b = blockIdx.x, tid = threadIdx.x;
  const int o = tid >> 1, half = tid & 1;
  const float* src = half ? (tgt + b * (T_ * H_)) : (hfin + b * H_);
  const float* wrow = w + o * 256 + half * 128;
  float acc = 0.0f;
#pragma unroll 8
  for (int k = 0; k < 128; k += 4) {
    float4 sv = *(const float4*)(src + k);
    float4 wv = *(const float4*)(wrow + k);
    acc += sv.x * wv.x + sv.y * wv.y + sv.z * wv.z + sv.w * wv.w;
  }
  acc += __shfl_xor(acc, 1);
  if (half == 0) out[b * H_ + o] = acc + bias[o];
}

extern "C" void kernel_launch(void* const* d_in, const int* in_sizes, int n_in,
                              void* d_out, int out_size, void* d_ws, size_t ws_size,
                              hipStream_t stream) {
  const float* targets = (const float*)d_in[0];
  const float* history = (const float*)d_in[1];
  const float* W_w = (const float*)d_in[2];
  const float* W_b = (const float*)d_in[3];
  const float* xu_w = (const float*)d_in[4];
  const float* xu_b = (const float*)d_in[5];
  const float* hu_w = (const float*)d_in[6];
  const float* hu_b = (const float*)d_in[7];
  const float* xr_w = (const float*)d_in[8];
  const float* xr_b = (const float*)d_in[9];
  const float* hr_w = (const float*)d_in[10];
  const float* hr_b = (const float*)d_in[11];
  const float* xg_w = (const float*)d_in[12];
  const float* xg_b = (const float*)d_in[13];
  const float* hg_w = (const float*)d_in[14];
  const float* hg_b = (const float*)d_in[15];
  const float* ln2_w = (const float*)d_in[16];
  const float* ln2_b = (const float*)d_in[17];
  float* out = (float*)d_out;
  float* att = (float*)d_ws;              // [B,T] f32 = 819200 B
  float* hfin = att + B_ * T_;            // [B,H] f32 = 524288 B

  scores_softmax_kernel<<<dim3(B_), dim3(256), 0, stream>>>(targets, history, W_w, W_b, att);
  scan_kernel<<<dim3(B_ / 16), dim3(256), 0, stream>>>(history, xu_w, xu_b, hu_w, hu_b,
                                                       xr_w, xr_b, hr_w, hr_b,
                                                       xg_w, xg_b, hg_w, hg_b, att, hfin);
  final_kernel<<<dim3(B_), dim3(256), 0, stream>>>(targets, hfin, ln2_w, ln2_b, out);
}

// Round 2
// 592.474 us; speedup vs baseline: 1.1272x; 1.1272x over previous
//
#include <hip/hip_runtime.h>

#define B_ 1024
#define T_ 200
#define H_ 128

typedef __attribute__((ext_vector_type(8))) short short8;
typedef __attribute__((ext_vector_type(4))) float f32x4;

#define MFMA(a, b, c) __builtin_amdgcn_mfma_f32_16x16x32_bf16((a), (b), (c), 0, 0, 0)

static __device__ __forceinline__ short f2bf(float f) {
  unsigned u = __float_as_uint(f);
  u += 0x7fffu + ((u >> 16) & 1u);  // RNE
  return (short)(u >> 16);
}
static __device__ __forceinline__ float bf2f(short s) {
  return __uint_as_float(((unsigned)(unsigned short)s) << 16);
}
// pack_hi(lo,hi): 32-bit word = [lo.hi16 | hi.hi16<<16]  (bf16 truncation of both)
static __device__ __forceinline__ unsigned pack_hi(float lo, float hi) {
  return __builtin_amdgcn_perm(__float_as_uint(hi), __float_as_uint(lo), 0x07060302u);
}
static __device__ __forceinline__ float trunc_bf(float f) {
  return __uint_as_float(__float_as_uint(f) & 0xFFFF0000u);
}
// CK-style barrier: LDS-only drain, does NOT drain vmcnt (keeps global prefetch alive)
static __device__ __forceinline__ void ck_barrier() {
  asm volatile("s_waitcnt lgkmcnt(0)\n\ts_barrier" ::: "memory");
}

// ---------------------------------------------------------------------------
// K_A: fused x-projections (xu/xr/xg, bf16) + attention scores (split bf16,
// fp32-grade). Grid (13 t-chunks, 64 row-groups), 512 threads = 8 waves;
// wave w owns output coltile w for all 4 matmuls. Double-buffered fp32 LDS
// staging of hist/tgt tiles with one-tile-ahead global prefetch.
// xpack layout: shorts, idx = (((bb*200+t)*3+mat)*512 + tid)*4  (short4/lane)
// ---------------------------------------------------------------------------
__global__ __launch_bounds__(512, 1) void proj_scores_kernel(
    const float* __restrict__ tgt, const float* __restrict__ hist,
    const float* __restrict__ Ww, const float* __restrict__ Wb,
    const float* __restrict__ xu_w, const float* __restrict__ xr_w,
    const float* __restrict__ xg_w,
    float* __restrict__ scores, short* __restrict__ xpack) {
  const int tc = blockIdx.x, bb = blockIdx.y;
  const int nt = (tc == 12) ? 8 : 16;
  const int t0 = tc * 16;
  const int tid = threadIdx.x;
  const int lane = tid & 63, w = tid >> 6;
  const int n = lane & 15, q = lane >> 4;

  __shared__ float hist_f[2][16 * 128];
  __shared__ float tgt_f[2][16 * 128];
  __shared__ float sp[16 * 8];

  // register B-frags: Ww hi/lo + 3 x-mats, each for this wave's coltile only
  short8 whi[4], wlo[4], wx[3][4];
  float wb;
  {
    const int o = w * 16 + n;
    wb = Wb[o];
    const float* Wm[3] = {xu_w, xr_w, xg_w};
#pragma unroll
    for (int ks = 0; ks < 4; ++ks) {
      const float* p = Ww + o * H_ + ks * 32 + q * 8;
      short8 h, l;
#pragma unroll
      for (int j = 0; j < 8; ++j) {
        float f = p[j];
        short hv = f2bf(f);
        h[j] = hv;
        l[j] = f2bf(f - bf2f(hv));
      }
      whi[ks] = h;
      wlo[ks] = l;
#pragma unroll
      for (int M = 0; M < 3; ++M) {
        const float* pm = Wm[M] + o * H_ + ks * 32 + q * 8;
        short8 v;
#pragma unroll
        for (int j = 0; j < 8; ++j) v[j] = f2bf(pm[j]);
        wx[M][ks] = v;
      }
    }
  }

  const int sm = tid >> 5, cs = tid & 31;  // staging: row, 4-float chunk
  const int spos = sm * 128 + ((cs ^ (sm & 7))) * 4;
  const size_t rowbase = ((size_t)(bb * 16 + sm) * T_) * H_ + cs * 4;

  float4 hv = *(const float4*)(hist + rowbase + (size_t)t0 * H_);
  float4 tv = *(const float4*)(tgt + rowbase + (size_t)t0 * H_);
  *(float4*)&hist_f[0][spos] = hv;
  *(float4*)&tgt_f[0][spos] = tv;
  ck_barrier();

  for (int tl = 0; tl < nt; ++tl) {
    const int cur = tl & 1;
    const bool have_next = (tl + 1 < nt);
    if (have_next) {
      hv = *(const float4*)(hist + rowbase + (size_t)(t0 + tl + 1) * H_);
      tv = *(const float4*)(tgt + rowbase + (size_t)(t0 + tl + 1) * H_);
    }
    f32x4 s1 = {0, 0, 0, 0}, s2 = {0, 0, 0, 0}, s3 = {0, 0, 0, 0};
    f32x4 ax0 = {0, 0, 0, 0}, ax1 = {0, 0, 0, 0}, ax2 = {0, 0, 0, 0};
#pragma unroll
    for (int ks = 0; ks < 4; ++ks) {
      // targets frag (fp32 -> hi/lo bf16 split; hi=trunc, lo=exact residual trunc)
      float4 ta = *(const float4*)&tgt_f[cur][n * 128 + ((ks * 8 + 2 * q) ^ (n & 7)) * 4];
      float4 tb = *(const float4*)&tgt_f[cur][n * 128 + ((ks * 8 + 2 * q + 1) ^ (n & 7)) * 4];
      union { short8 s; unsigned u[4]; } Ahi, Alo;
      Ahi.u[0] = pack_hi(ta.x, ta.y);
      Ahi.u[1] = pack_hi(ta.z, ta.w);
      Ahi.u[2] = pack_hi(tb.x, tb.y);
      Ahi.u[3] = pack_hi(tb.z, tb.w);
      Alo.u[0] = pack_hi(ta.x - trunc_bf(ta.x), ta.y - trunc_bf(ta.y));
      Alo.u[1] = pack_hi(ta.z - trunc_bf(ta.z), ta.w - trunc_bf(ta.w));
      Alo.u[2] = pack_hi(tb.x - trunc_bf(tb.x), tb.y - trunc_bf(tb.y));
      Alo.u[3] = pack_hi(tb.z - trunc_bf(tb.z), tb.w - trunc_bf(tb.w));
      s1 = MFMA(Ahi.s, whi[ks], s1);
      s2 = MFMA(Ahi.s, wlo[ks], s2);
      s3 = MFMA(Alo.s, whi[ks], s3);
      // hist frag (trunc bf16)
      float4 ha = *(const float4*)&hist_f[cur][n * 128 + ((ks * 8 + 2 * q) ^ (n & 7)) * 4];
      float4 hb = *(const float4*)&hist_f[cur][n * 128 + ((ks * 8 + 2 * q + 1) ^ (n & 7)) * 4];
      union { short8 s; unsigned u[4]; } Ah;
      Ah.u[0] = pack_hi(ha.x, ha.y);
      Ah.u[1] = pack_hi(ha.z, ha.w);
      Ah.u[2] = pack_hi(hb.x, hb.y);
      Ah.u[3] = pack_hi(hb.z, hb.w);
      ax0 = MFMA(Ah.s, wx[0][ks], ax0);
      ax1 = MFMA(Ah.s, wx[1][ks], ax1);
      ax2 = MFMA(Ah.s, wx[2][ks], ax2);
    }
    // score partials: (aw+Wb) .* hist over this wave's 16 cols
#pragma unroll
    for (int r = 0; r < 4; ++r) {
      const int m = q * 4 + r;
      const int col = w * 16 + n;
      float histv = hist_f[cur][m * 128 + (((col >> 2) ^ (m & 7))) * 4 + (col & 3)];
      float v = (s1[r] + s2[r] + s3[r] + wb) * histv;
      v += __shfl_xor(v, 1);
      v += __shfl_xor(v, 2);
      v += __shfl_xor(v, 4);
      v += __shfl_xor(v, 8);
      if (n == 0) sp[m * 8 + w] = v;
    }
    // x-projection packed store (bf16-trunc), scan-native layout
    if (xpack != nullptr) {
      const size_t base = (((size_t)(bb * T_ + t0 + tl) * 3) * 512 + tid);
      uint2 u;
      u.x = pack_hi(ax0[0], ax0[1]); u.y = pack_hi(ax0[2], ax0[3]);
      *(uint2*)(xpack + (base + 0 * 512) * 4) = u;
      u.x = pack_hi(ax1[0], ax1[1]); u.y = pack_hi(ax1[2], ax1[3]);
      *(uint2*)(xpack + (base + 1 * 512) * 4) = u;
      u.x = pack_hi(ax2[0], ax2[1]); u.y = pack_hi(ax2[2], ax2[3]);
      *(uint2*)(xpack + (base + 2 * 512) * 4) = u;
    }
    ck_barrier();
    if (tid < 16) {
      float s = 0.0f;
#pragma unroll
      for (int ww = 0; ww < 8; ++ww) s += sp[tid * 8 + ww];
      scores[(size_t)(bb * 16 + tid) * T_ + (t0 + tl)] = s;
    }
    if (have_next) {
      *(float4*)&hist_f[cur ^ 1][spos] = hv;
      *(float4*)&tgt_f[cur ^ 1][spos] = tv;
    }
    ck_barrier();
  }
}

// ---------------------------------------------------------------------------
// K_B: softmax over T, in place on the scores buffer. One block per batch row.
// ---------------------------------------------------------------------------
__global__ __launch_bounds__(256, 4) void softmax_kernel(float* __restrict__ att) {
  const int b = blockIdx.x, tid = threadIdx.x;
  const int lane = tid & 63, wave = tid >> 6;
  __shared__ float red[8];
  float v = (tid < T_) ? att[(size_t)b * T_ + tid] : -3.0e38f;
  float mx = v;
#pragma unroll
  for (int d = 1; d < 64; d <<= 1) mx = fmaxf(mx, __shfl_xor(mx, d));
  if (lane == 0) red[wave] = mx;
  __syncthreads();
  mx = fmaxf(fmaxf(red[0], red[1]), fmaxf(red[2], red[3]));
  float e = (tid < T_) ? __expf(v - mx) : 0.0f;
  float sm = e;
#pragma unroll
  for (int d = 1; d < 64; d <<= 1) sm += __shfl_xor(sm, d);
  if (lane == 0) red[4 + wave] = sm;
  __syncthreads();
  sm = red[4] + red[5] + red[6] + red[7];
  if (tid < T_) att[(size_t)b * T_ + tid] = e / sm;
}

// ---------------------------------------------------------------------------
// K_C: recurrent scan. 64 blocks x 16 rows, 512 threads (8 waves, wave w owns
// output coltile w). Only the 3 h-matvecs in the loop (12 MFMA/wave/step).
// XP=true: x-projections read from xpack, depth-4 register prefetch, barriers
// never drain vmcnt (ck_barrier). XP=false: x computed in-scan (fallback).
// ---------------------------------------------------------------------------
template <bool XP>
__global__ __launch_bounds__(512, 1) void scan2_kernel(
    const float* __restrict__ hist,
    const float* __restrict__ xu_w, const float* __restrict__ xu_b,
    const float* __restrict__ hu_w, const float* __restrict__ hu_b,
    const float* __restrict__ xr_w, const float* __restrict__ xr_b,
    const float* __restrict__ hr_w, const float* __restrict__ hr_b,
    const float* __restrict__ xg_w, const float* __restrict__ xg_b,
    const float* __restrict__ hg_w, const float* __restrict__ hg_b,
    const float* __restrict__ att, const short* __restrict__ xpack,
    float* __restrict__ h_out) {
  const int tid = threadIdx.x;
  const int lane = tid & 63, w = tid >> 6;
  const int n = lane & 15, q = lane >> 4;
  const int bb = blockIdx.x, r0 = bb * 16;
  const int o = w * 16 + n;

  __shared__ short hbuf[2][16 * 128];
  __shared__ short xbuf[2][16 * 128];   // used only when !XP
  __shared__ float att_l[16 * 201];     // stride 201: kills 4-way bank conflict

  short8 wh[3][4];
  {
    const float* Hm[3] = {hu_w, hr_w, hg_w};
#pragma unroll
    for (int M = 0; M < 3; ++M)
#pragma unroll
      for (int ks = 0; ks < 4; ++ks) {
        const float* p = Hm[M] + o * H_ + ks * 32 + q * 8;
        short8 v;
#pragma unroll
        for (int j = 0; j < 8; ++j) v[j] = f2bf(p[j]);
        wh[M][ks] = v;
      }
  }
  short8 wxf[3][4];
  if constexpr (!XP) {
    const float* Xm[3] = {xu_w, xr_w, xg_w};
#pragma unroll
    for (int M = 0; M < 3; ++M)
#pragma unroll
      for (int ks = 0; ks < 4; ++ks) {
        const float* p = Xm[M] + o * H_ + ks * 32 + q * 8;
        short8 v;
#pragma unroll
        for (int j = 0; j < 8; ++j) v[j] = f2bf(p[j]);
        wxf[M][ks] = v;
      }
  }
  const float bu = xu_b[o] + hu_b[o];
  const float br_ = xr_b[o] + hr_b[o];
  const float bxg = xg_b[o], bhg = hg_b[o];

  for (int i = tid; i < 16 * T_; i += 512) {
    int m = i / T_, tt = i - m * T_;
    att_l[m * 201 + tt] = att[(size_t)r0 * T_ + i];
  }
  for (int i = tid; i < 16 * 128; i += 512) hbuf[0][i] = 0;

  // x prefetch state
  uint2 ring[4][3];
  const int sm = tid >> 5, cs = tid & 31;
  const int xpos = sm * 128 + (((cs >> 1) ^ (sm & 7))) * 8 + (cs & 1) * 4;
  const float* hrow = hist + ((size_t)(r0 + sm) * T_) * H_ + cs * 4;
  float4 xr0;
  if constexpr (XP) {
#pragma unroll
    for (int s = 0; s < 4; ++s)
#pragma unroll
      for (int M = 0; M < 3; ++M)
        ring[s][M] = *(const uint2*)(xpack + ((((size_t)bb * T_ + s) * 3 + M) * 512 + tid) * 4);
  } else {
    float4 a = *(const float4*)hrow;  // x(0)
    uint2 u;
    u.x = pack_hi(a.x, a.y); u.y = pack_hi(a.z, a.w);
    *(uint2*)&xbuf[0][xpos] = u;
    xr0 = *(const float4*)(hrow + H_);  // x(1)
  }

  float hreg[4] = {0.0f, 0.0f, 0.0f, 0.0f};
  ck_barrier();

#pragma unroll 4
  for (int t = 0; t < T_; ++t) {
    const int cur = t & 1, nxt = cur ^ 1;
    short8 ha[4];
#pragma unroll
    for (int ks = 0; ks < 4; ++ks)
      ha[ks] = *(short8*)&hbuf[cur][n * 128 + ((ks * 4 + q) ^ (n & 7)) * 8];
    short8 xa[4];
    if constexpr (!XP) {
#pragma unroll
      for (int ks = 0; ks < 4; ++ks)
        xa[ks] = *(short8*)&xbuf[cur][n * 128 + ((ks * 4 + q) ^ (n & 7)) * 8];
    }
    f32x4 au = {0, 0, 0, 0}, ar = {0, 0, 0, 0}, ag = {0, 0, 0, 0};
    f32x4 axu = {0, 0, 0, 0}, axr = {0, 0, 0, 0}, axg = {0, 0, 0, 0};
#pragma unroll
    for (int ks = 0; ks < 4; ++ks) {
      au = MFMA(ha[ks], wh[0][ks], au);
      ar = MFMA(ha[ks], wh[1][ks], ar);
      ag = MFMA(ha[ks], wh[2][ks], ag);
      if constexpr (!XP) {
        axu = MFMA(xa[ks], wxf[0][ks], axu);
        axr = MFMA(xa[ks], wxf[1][ks], axr);
        axg = MFMA(xa[ks], wxf[2][ks], axg);
      }
    }
    float xu_f[4], xr_f[4], xg_f[4];
    if constexpr (XP) {
      const int sl = t & 3;
      uint2 u0 = ring[sl][0], u1 = ring[sl][1], u2 = ring[sl][2];
      xu_f[0] = __uint_as_float(u0.x << 16); xu_f[1] = __uint_as_float(u0.x & 0xFFFF0000u);
      xu_f[2] = __uint_as_float(u0.y << 16); xu_f[3] = __uint_as_float(u0.y & 0xFFFF0000u);
      xr_f[0] = __uint_as_float(u1.x << 16); xr_f[1] = __uint_as_float(u1.x & 0xFFFF0000u);
      xr_f[2] = __uint_as_float(u1.y << 16); xr_f[3] = __uint_as_float(u1.y & 0xFFFF0000u);
      xg_f[0] = __uint_as_float(u2.x << 16); xg_f[1] = __uint_as_float(u2.x & 0xFFFF0000u);
      xg_f[2] = __uint_as_float(u2.y << 16); xg_f[3] = __uint_as_float(u2.y & 0xFFFF0000u);
      const int tp = (t + 4 < T_) ? t + 4 : T_ - 1;
#pragma unroll
      for (int M = 0; M < 3; ++M)
        ring[sl][M] = *(const uint2*)(xpack + ((((size_t)bb * T_ + tp) * 3 + M) * 512 + tid) * 4);
    } else {
#pragma unroll
      for (int r = 0; r < 4; ++r) { xu_f[r] = axu[r]; xr_f[r] = axr[r]; xg_f[r] = axg[r]; }
      uint2 u;
      u.x = pack_hi(xr0.x, xr0.y); u.y = pack_hi(xr0.z, xr0.w);
      *(uint2*)&xbuf[nxt][xpos] = u;  // stage x(t+1)
      const int tp = (t + 2 < T_) ? t + 2 : T_ - 1;
      xr0 = *(const float4*)(hrow + (size_t)tp * H_);
    }
    // gates + h update
#pragma unroll
    for (int r = 0; r < 4; ++r) {
      const int m = q * 4 + r;
      const float a_t = att_l[m * 201 + t];
      const float u = a_t / (1.0f + __expf(-(xu_f[r] + au[r] + bu)));
      const float rr = 1.0f / (1.0f + __expf(-(xr_f[r] + ar[r] + br_)));
      const float sg = (xg_f[r] + bxg) + rr * (ag[r] + bhg);
      const float e2 = __expf(2.0f * sg);
      const float g = 1.0f - 2.0f / (e2 + 1.0f);
      const float hn = hreg[r] + u * (g - hreg[r]);
      hreg[r] = hn;
      hbuf[nxt][m * 128 + ((o >> 3) ^ (m & 7)) * 8 + (o & 7)] =
          (short)(__float_as_uint(hn) >> 16);
      if (t == T_ - 1) h_out[(size_t)(r0 + m) * H_ + o] = hn;
    }
    ck_barrier();
  }
}

// ---------------------------------------------------------------------------
// K_D: out = [h | targets[:,0]] @ ln2_w^T + ln2_b (fp32)
// ---------------------------------------------------------------------------
__global__ __launch_bounds__(256, 4) void final_kernel(
    const float* __restrict__ tgt, const float* __restrict__ hfin,
    const float* __restrict__ w, const float* __restrict__ bias,
    float* __restrict__ out) {
  const int b = blockIdx.x, tid = threadIdx.x;
  const int o = tid >> 1, half = tid & 1;
  const float* src = half ? (tgt + (size_t)b * (T_ * H_)) : (hfin + (size_t)b * H_);
  const float* wrow = w + o * 256 + half * 128;
  float acc = 0.0f;
#pragma unroll 8
  for (int k = 0; k < 128; k += 4) {
    float4 sv = *(const float4*)(src + k);
    float4 wv = *(const float4*)(wrow + k);
    acc += sv.x * wv.x + sv.y * wv.y + sv.z * wv.z + sv.w * wv.w;
  }
  acc += __shfl_xor(acc, 1);
  if (half == 0) out[(size_t)b * H_ + o] = acc + bias[o];
}

extern "C" void kernel_launch(void* const* d_in, const int* in_sizes, int n_in,
                              void* d_out, int out_size, void* d_ws, size_t ws_size,
                              hipStream_t stream) {
  const float* targets = (const float*)d_in[0];
  const float* history = (const float*)d_in[1];
  const float* W_w = (const float*)d_in[2];
  const float* W_b = (const float*)d_in[3];
  const float* xu_w = (const float*)d_in[4];
  const float* xu_b = (const float*)d_in[5];
  const float* hu_w = (const float*)d_in[6];
  const float* hu_b = (const float*)d_in[7];
  const float* xr_w = (const float*)d_in[8];
  const float* xr_b = (const float*)d_in[9];
  const float* hr_w = (const float*)d_in[10];
  const float* hr_b = (const float*)d_in[11];
  const float* xg_w = (const float*)d_in[12];
  const float* xg_b = (const float*)d_in[13];
  const float* hg_w = (const float*)d_in[14];
  const float* hg_b = (const float*)d_in[15];
  const float* ln2_w = (const float*)d_in[16];
  const float* ln2_b = (const float*)d_in[17];
  float* out = (float*)d_out;

  float* att = (float*)d_ws;                       // [B,T] f32, scores then softmax in place
  float* hfin = att + (size_t)B_ * T_;             // [B,H] f32
  const size_t fixed = (size_t)B_ * T_ * 4 + (size_t)B_ * H_ * 4;
  const size_t xpack_bytes = (size_t)64 * T_ * 3 * 512 * 4 * 2;  // 157,286,400
  short* xpack = (ws_size >= fixed + xpack_bytes)
                     ? (short*)((char*)d_ws + fixed)
                     : nullptr;

  proj_scores_kernel<<<dim3(13, 64), dim3(512), 0, stream>>>(
      targets, history, W_w, W_b, xu_w, xr_w, xg_w, att, xpack);
  softmax_kernel<<<dim3(B_), dim3(256), 0, stream>>>(att);
  if (xpack) {
    scan2_kernel<true><<<dim3(64), dim3(512), 0, stream>>>(
        history, xu_w, xu_b, hu_w, hu_b, xr_w, xr_b, hr_w, hr_b,
        xg_w, xg_b, hg_w, hg_b, att, xpack, hfin);
  } else {
    scan2_kernel<false><<<dim3(64), dim3(512), 0, stream>>>(
        history, xu_w, xu_b, hu_w, hu_b, xr_w, xr_b, hr_w, hr_b,
        xg_w, xg_b, hg_w, hg_b, att, xpack, hfin);
  }
  final_kernel<<<dim3(B_), dim3(256), 0, stream>>>(targets, hfin, ln2_w, ln2_b, out);
}

// Round 3
// 498.029 us; speedup vs baseline: 1.3410x; 1.1896x over previous
//
#include <hip/hip_runtime.h>

#define B_ 1024
#define T_ 200
#define H_ 128

typedef __attribute__((ext_vector_type(8))) short short8;
typedef __attribute__((ext_vector_type(4))) float f32x4;

#define MFMA(a, b, c) __builtin_amdgcn_mfma_f32_16x16x32_bf16((a), (b), (c), 0, 0, 0)

static __device__ __forceinline__ short f2bf(float f) {
  unsigned u = __float_as_uint(f);
  u += 0x7fffu + ((u >> 16) & 1u);  // RNE
  return (short)(u >> 16);
}
static __device__ __forceinline__ float bf2f(short s) {
  return __uint_as_float(((unsigned)(unsigned short)s) << 16);
}
// pack two floats as bf16 (RNE) into one dword: low short = a, high short = b
static __device__ __forceinline__ unsigned pack2bf_rne(float a, float b) {
  unsigned ua = __float_as_uint(a);
  ua += 0x7fffu + ((ua >> 16) & 1u);
  unsigned ub = __float_as_uint(b);
  ub += 0x7fffu + ((ub >> 16) & 1u);
  return (ua >> 16) | (ub & 0xFFFF0000u);
}
static __device__ __forceinline__ float rcp_f(float x) { return __builtin_amdgcn_rcpf(x); }
// CK-style barrier: LDS-only drain, does NOT drain vmcnt (keeps global prefetch alive)
static __device__ __forceinline__ void ck_barrier() {
  asm volatile("s_waitcnt lgkmcnt(0)\n\ts_barrier" ::: "memory");
}

// ---------------------------------------------------------------------------
// K_A: attention scores (split bf16 3-pass, fp32-grade) + hist->bf16 repack
// into scan-native A-fragment-direct global layout.
// Grid (13 t-chunks, 64 row-groups) x 512 threads (8 waves, wave w = coltile w).
// Conversion fp32->bf16 happens ONCE at staging (not per wave).
// histbf layout (shorts): ((bb*200+t)*4 + ks)*512 + wl*8 + j
//   holds hist[row=bb*16+(wl&15)][k=ks*32+(wl>>4)*8+j], wl = wave-lane 0..63.
// ---------------------------------------------------------------------------
__global__ __launch_bounds__(512, 1) void proj_scores_kernel(
    const float* __restrict__ tgt, const float* __restrict__ hist,
    const float* __restrict__ Ww, const float* __restrict__ Wb,
    float* __restrict__ scores, short* __restrict__ histbf) {
  const int tc = blockIdx.x, bb = blockIdx.y;
  const int nt = (tc == 12) ? 8 : 16;
  const int t0 = tc * 16;
  const int tid = threadIdx.x;
  const int lane = tid & 63, w = tid >> 6;
  const int n = lane & 15, q = lane >> 4;

  __shared__ short tgt_hi[2][16 * 128];
  __shared__ short tgt_lo[2][16 * 128];
  __shared__ float hist_f[2][16 * 132];  // padded rows
  __shared__ float sp[16 * 8];

  // register B-frags for Ww (hi/lo split), this wave's coltile
  short8 whi[4], wlo[4];
  float wb;
  {
    const int o = w * 16 + n;
    wb = Wb[o];
#pragma unroll
    for (int ks = 0; ks < 4; ++ks) {
      const float* p = Ww + o * H_ + ks * 32 + q * 8;
      short8 h, l;
#pragma unroll
      for (int j = 0; j < 8; ++j) {
        float f = p[j];
        short hv = f2bf(f);
        h[j] = hv;
        l[j] = f2bf(f - bf2f(hv));
      }
      whi[ks] = h;
      wlo[ks] = l;
    }
  }

  // staging: thread -> (row sm, 4-float granule cs)
  const int sm = tid >> 5, cs = tid & 31;
  const int g = cs >> 1, half = cs & 1;
  const int spos16 = sm * 128 + ((g ^ (sm & 7)) * 8) + half * 4;  // shorts
  const int sposf = sm * 132 + cs * 4;                            // floats
  const size_t rowbase = ((size_t)(bb * 16 + sm) * T_) * H_ + cs * 4;

  // histbf conversion mapping: thread handles 8 bytes (4 shorts)
  const int cu = tid;
  const int cks = cu >> 7, crem = cu & 127, cwl = crem >> 1, chalf = crem & 1;
  const int crow = cwl & 15, ckb = cks * 32 + (cwl >> 4) * 8 + chalf * 4;

  float4 hv = *(const float4*)(hist + rowbase + (size_t)t0 * H_);
  float4 tv = *(const float4*)(tgt + rowbase + (size_t)t0 * H_);
  {
    *(float4*)&hist_f[0][sposf] = hv;
    uint2 hi, lo;
    hi.x = pack2bf_rne(tv.x, tv.y);
    hi.y = pack2bf_rne(tv.z, tv.w);
    lo.x = pack2bf_rne(tv.x - bf2f((short)(hi.x)), tv.y - bf2f((short)(hi.x >> 16)));
    lo.y = pack2bf_rne(tv.z - bf2f((short)(hi.y)), tv.w - bf2f((short)(hi.y >> 16)));
    *(uint2*)&tgt_hi[0][spos16] = hi;
    *(uint2*)&tgt_lo[0][spos16] = lo;
  }
  ck_barrier();

  for (int tl = 0; tl < nt; ++tl) {
    const int cur = tl & 1, nxt = cur ^ 1;
    const bool have_next = (tl + 1 < nt);
    if (have_next) {
      hv = *(const float4*)(hist + rowbase + (size_t)(t0 + tl + 1) * H_);
      tv = *(const float4*)(tgt + rowbase + (size_t)(t0 + tl + 1) * H_);
    }
    // scores MFMA: 3-pass split bf16
    f32x4 s1 = {0, 0, 0, 0}, s2 = {0, 0, 0, 0}, s3 = {0, 0, 0, 0};
#pragma unroll
    for (int ks = 0; ks < 4; ++ks) {
      const int fp = n * 128 + ((ks * 4 + q) ^ (n & 7)) * 8;
      short8 ahi = *(short8*)&tgt_hi[cur][fp];
      short8 alo = *(short8*)&tgt_lo[cur][fp];
      s1 = MFMA(ahi, whi[ks], s1);
      s2 = MFMA(ahi, wlo[ks], s2);
      s3 = MFMA(alo, whi[ks], s3);
    }
    // dot with hist (fp32) + in-wave n-reduction
#pragma unroll
    for (int r = 0; r < 4; ++r) {
      const int m = q * 4 + r;
      float v = (s1[r] + s2[r] + s3[r] + wb) * hist_f[cur][m * 132 + w * 16 + n];
      v += __shfl_xor(v, 1);
      v += __shfl_xor(v, 2);
      v += __shfl_xor(v, 4);
      v += __shfl_xor(v, 8);
      if (n == 0) sp[m * 8 + w] = v;
    }
    // hist -> bf16 packed global (scan-native layout), once per element
    if (histbf != nullptr) {
      const float* src = &hist_f[cur][crow * 132 + ckb];
      uint2 u;
      u.x = pack2bf_rne(src[0], src[1]);
      u.y = pack2bf_rne(src[2], src[3]);
      const size_t sb = (((size_t)(bb * T_ + t0 + tl) * 4) + cks) * 512 + cwl * 8 + chalf * 4;
      *(uint2*)(histbf + sb) = u;
    }
    // stage next tile (prefetched regs)
    if (have_next) {
      *(float4*)&hist_f[nxt][sposf] = hv;
      uint2 hi, lo;
      hi.x = pack2bf_rne(tv.x, tv.y);
      hi.y = pack2bf_rne(tv.z, tv.w);
      lo.x = pack2bf_rne(tv.x - bf2f((short)(hi.x)), tv.y - bf2f((short)(hi.x >> 16)));
      lo.y = pack2bf_rne(tv.z - bf2f((short)(hi.y)), tv.w - bf2f((short)(hi.y >> 16)));
      *(uint2*)&tgt_hi[nxt][spos16] = hi;
      *(uint2*)&tgt_lo[nxt][spos16] = lo;
    }
    ck_barrier();
    if (tid < 16) {
      float s = 0.0f;
#pragma unroll
      for (int ww = 0; ww < 8; ++ww) s += sp[tid * 8 + ww];
      scores[(size_t)(bb * 16 + tid) * T_ + (t0 + tl)] = s;
    }
    ck_barrier();
  }
}

// ---------------------------------------------------------------------------
// K_B: softmax over T, in place. One block per batch row.
// ---------------------------------------------------------------------------
__global__ __launch_bounds__(256, 4) void softmax_kernel(float* __restrict__ att) {
  const int b = blockIdx.x, tid = threadIdx.x;
  const int lane = tid & 63, wave = tid >> 6;
  __shared__ float red[8];
  float v = (tid < T_) ? att[(size_t)b * T_ + tid] : -3.0e38f;
  float mx = v;
#pragma unroll
  for (int d = 1; d < 64; d <<= 1) mx = fmaxf(mx, __shfl_xor(mx, d));
  if (lane == 0) red[wave] = mx;
  __syncthreads();
  mx = fmaxf(fmaxf(red[0], red[1]), fmaxf(red[2], red[3]));
  float e = (tid < T_) ? __expf(v - mx) : 0.0f;
  float sm = e;
#pragma unroll
  for (int d = 1; d < 64; d <<= 1) sm += __shfl_xor(sm, d);
  if (lane == 0) red[4 + wave] = sm;
  __syncthreads();
  sm = red[4] + red[5] + red[6] + red[7];
  if (tid < T_) att[(size_t)b * T_ + tid] = e / sm;
}

// ---------------------------------------------------------------------------
// K_C: recurrent scan v3. 64 blocks x 16 rows, 512 threads (8 waves, wave w =
// coltile w). All 6 matmuls in-scan (24 MFMA/wave/step). DIRECT path: x
// A-frags loaded straight from histbf global (coalesced, L1-served, no LDS),
// depth-2 register prefetch; att also prefetched from global (L1-resident).
// Gates use v_rcp/v_exp only (no IEEE division). One lgkm-only barrier/step.
// ---------------------------------------------------------------------------
template <bool DIRECT>
__global__ __launch_bounds__(512, 2) void scan3_kernel(
    const float* __restrict__ hist,
    const float* __restrict__ xu_w, const float* __restrict__ xu_b,
    const float* __restrict__ hu_w, const float* __restrict__ hu_b,
    const float* __restrict__ xr_w, const float* __restrict__ xr_b,
    const float* __restrict__ hr_w, const float* __restrict__ hr_b,
    const float* __restrict__ xg_w, const float* __restrict__ xg_b,
    const float* __restrict__ hg_w, const float* __restrict__ hg_b,
    const float* __restrict__ att, const short* __restrict__ histbf,
    float* __restrict__ h_out) {
  const int tid = threadIdx.x;
  const int lane = tid & 63, w = tid >> 6;
  const int n = lane & 15, q = lane >> 4;
  const int bb = blockIdx.x, r0 = bb * 16;
  const int o = w * 16 + n;

  __shared__ short hbuf[2][16 * 128];
  __shared__ short xbuf[2][16 * 128];  // only used when !DIRECT

  // B-frags: 0=xu 1=hu 2=xr 3=hr 4=xg 5=hg  (96 VGPRs)
  short8 wf[6][4];
  {
    const float* Wm[6] = {xu_w, hu_w, xr_w, hr_w, xg_w, hg_w};
#pragma unroll
    for (int M = 0; M < 6; ++M)
#pragma unroll
      for (int ks = 0; ks < 4; ++ks) {
        const float* p = Wm[M] + o * H_ + ks * 32 + q * 8;
        short8 v;
#pragma unroll
        for (int j = 0; j < 8; ++j) v[j] = f2bf(p[j]);
        wf[M][ks] = v;
      }
  }
  const float bu = xu_b[o] + hu_b[o];
  const float br_ = xr_b[o] + hr_b[o];
  const float bxg = xg_b[o], bhg = hg_b[o];

  for (int i = tid; i < 16 * 128; i += 512) hbuf[0][i] = 0;

  // --- x-fragment prefetch state ---
  typedef union { uint4 u; short8 s; } frag_u;
  frag_u xp[2][4];
  const short* px = histbf + ((size_t)bb * T_ * 4) * 512 + (size_t)lane * 8;
  // --- fallback staging state ---
  const int sm = tid >> 5, cs = tid & 31;
  const int xpos = sm * 128 + (((cs >> 1) ^ (sm & 7)) * 8) + (cs & 1) * 4;
  const float* hrow = hist + ((size_t)(r0 + sm) * T_) * H_ + cs * 4;
  float4 xnext;

  if constexpr (DIRECT) {
#pragma unroll
    for (int s = 0; s < 2; ++s)
#pragma unroll
      for (int ks = 0; ks < 4; ++ks)
        xp[s][ks].u = *(const uint4*)(px + (size_t)(s * 4 + ks) * 512);
  } else {
    float4 a = *(const float4*)hrow;  // x(0)
    uint2 u;
    u.x = pack2bf_rne(a.x, a.y);
    u.y = pack2bf_rne(a.z, a.w);
    *(uint2*)&xbuf[0][xpos] = u;
    xnext = *(const float4*)(hrow + H_);  // x(1)
  }

  // att prefetch (depth 2), rows m=q*4+r of this block, L1-resident (12.8 KB)
  float ap[2][4];
  const float* pa = att + (size_t)(r0 + q * 4) * T_;
#pragma unroll
  for (int s = 0; s < 2; ++s)
#pragma unroll
    for (int r = 0; r < 4; ++r) ap[s][r] = pa[(size_t)r * T_ + s];

  float hreg[4] = {0.0f, 0.0f, 0.0f, 0.0f};
  ck_barrier();

#pragma unroll 2
  for (int t = 0; t < T_; ++t) {
    const int cur = t & 1, nxt = cur ^ 1;
    short8 ha[4];
#pragma unroll
    for (int ks = 0; ks < 4; ++ks)
      ha[ks] = *(short8*)&hbuf[cur][n * 128 + ((ks * 4 + q) ^ (n & 7)) * 8];
    short8 xa[4];
    if constexpr (DIRECT) {
#pragma unroll
      for (int ks = 0; ks < 4; ++ks) xa[ks] = xp[cur][ks].s;
    } else {
#pragma unroll
      for (int ks = 0; ks < 4; ++ks)
        xa[ks] = *(short8*)&xbuf[cur][n * 128 + ((ks * 4 + q) ^ (n & 7)) * 8];
    }
    f32x4 axu = {0, 0, 0, 0}, ahu = {0, 0, 0, 0}, axr = {0, 0, 0, 0},
          ahr = {0, 0, 0, 0}, axg = {0, 0, 0, 0}, ahg = {0, 0, 0, 0};
#pragma unroll
    for (int ks = 0; ks < 4; ++ks) {
      axu = MFMA(xa[ks], wf[0][ks], axu);
      ahu = MFMA(ha[ks], wf[1][ks], ahu);
      axr = MFMA(xa[ks], wf[2][ks], axr);
      ahr = MFMA(ha[ks], wf[3][ks], ahr);
      axg = MFMA(xa[ks], wf[4][ks], axg);
      ahg = MFMA(ha[ks], wf[5][ks], ahg);
    }
    // issue prefetches for t+2 (vmcnt NOT drained by ck_barrier)
    const int tp = (t + 2 < T_) ? t + 2 : T_ - 1;
    if constexpr (DIRECT) {
#pragma unroll
      for (int ks = 0; ks < 4; ++ks)
        xp[cur][ks].u = *(const uint4*)(px + (size_t)(tp * 4 + ks) * 512);
    } else {
      uint2 u;
      u.x = pack2bf_rne(xnext.x, xnext.y);
      u.y = pack2bf_rne(xnext.z, xnext.w);
      *(uint2*)&xbuf[nxt][xpos] = u;  // stage x(t+1)
      xnext = *(const float4*)(hrow + (size_t)tp * H_);
    }
    float at_c[4];
#pragma unroll
    for (int r = 0; r < 4; ++r) {
      at_c[r] = ap[cur][r];
      ap[cur][r] = pa[(size_t)r * T_ + tp];
    }
    // gates + h update (rcp-based, no IEEE division)
#pragma unroll
    for (int r = 0; r < 4; ++r) {
      const int m = q * 4 + r;
      const float su = axu[r] + ahu[r] + bu;
      const float u = at_c[r] * rcp_f(1.0f + __expf(-su));
      const float sr = axr[r] + ahr[r] + br_;
      const float rr = rcp_f(1.0f + __expf(-sr));
      const float sg = (axg[r] + bxg) + rr * (ahg[r] + bhg);
      const float g = 2.0f * rcp_f(1.0f + __expf(-2.0f * sg)) - 1.0f;
      const float hn = hreg[r] + u * (g - hreg[r]);
      hreg[r] = hn;
      hbuf[nxt][m * 128 + ((o >> 3) ^ (m & 7)) * 8 + (o & 7)] =
          (short)(__float_as_uint(hn) >> 16);
      if (t == T_ - 1) h_out[(size_t)(r0 + m) * H_ + o] = hn;
    }
    ck_barrier();
  }
}

// ---------------------------------------------------------------------------
// K_D: out = [h | targets[:,0]] @ ln2_w^T + ln2_b (fp32)
// ---------------------------------------------------------------------------
__global__ __launch_bounds__(256, 4) void final_kernel(
    const float* __restrict__ tgt, const float* __restrict__ hfin,
    const float* __restrict__ w, const float* __restrict__ bias,
    float* __restrict__ out) {
  const int b = blockIdx.x, tid = threadIdx.x;
  const int o = tid >> 1, half = tid & 1;
  const float* src = half ? (tgt + (size_t)b * (T_ * H_)) : (hfin + (size_t)b * H_);
  const float* wrow = w + o * 256 + half * 128;
  float acc = 0.0f;
#pragma unroll 8
  for (int k = 0; k < 128; k += 4) {
    float4 sv = *(const float4*)(src + k);
    float4 wv = *(const float4*)(wrow + k);
    acc += sv.x * wv.x + sv.y * wv.y + sv.z * wv.z + sv.w * wv.w;
  }
  acc += __shfl_xor(acc, 1);
  if (half == 0) out[(size_t)b * H_ + o] = acc + bias[o];
}

extern "C" void kernel_launch(void* const* d_in, const int* in_sizes, int n_in,
                              void* d_out, int out_size, void* d_ws, size_t ws_size,
                              hipStream_t stream) {
  const float* targets = (const float*)d_in[0];
  const float* history = (const float*)d_in[1];
  const float* W_w = (const float*)d_in[2];
  const float* W_b = (const float*)d_in[3];
  const float* xu_w = (const float*)d_in[4];
  const float* xu_b = (const float*)d_in[5];
  const float* hu_w = (const float*)d_in[6];
  const float* hu_b = (const float*)d_in[7];
  const float* xr_w = (const float*)d_in[8];
  const float* xr_b = (const float*)d_in[9];
  const float* hr_w = (const float*)d_in[10];
  const float* hr_b = (const float*)d_in[11];
  const float* xg_w = (const float*)d_in[12];
  const float* xg_b = (const float*)d_in[13];
  const float* hg_w = (const float*)d_in[14];
  const float* hg_b = (const float*)d_in[15];
  const float* ln2_w = (const float*)d_in[16];
  const float* ln2_b = (const float*)d_in[17];
  float* out = (float*)d_out;

  float* att = (float*)d_ws;            // [B,T] f32
  float* hfin = att + (size_t)B_ * T_;  // [B,H] f32
  const size_t fixed = (size_t)B_ * T_ * 4 + (size_t)B_ * H_ * 4;
  const size_t histbf_bytes = (size_t)64 * T_ * 4 * 512 * 8 * 2;  // 52.4 MB
  short* histbf = (ws_size >= fixed + histbf_bytes)
                      ? (short*)((char*)d_ws + fixed)
                      : nullptr;

  proj_scores_kernel<<<dim3(13, 64), dim3(512), 0, stream>>>(
      targets, history, W_w, W_b, att, histbf);
  softmax_kernel<<<dim3(B_), dim3(256), 0, stream>>>(att);
  if (histbf) {
    scan3_kernel<true><<<dim3(64), dim3(512), 0, stream>>>(
        history, xu_w, xu_b, hu_w, hu_b, xr_w, xr_b, hr_w, hr_b,
        xg_w, xg_b, hg_w, hg_b, att, histbf, hfin);
  } else {
    scan3_kernel<false><<<dim3(64), dim3(512), 0, stream>>>(
        history, xu_w, xu_b, hu_w, hu_b, xr_w, xr_b, hr_w, hr_b,
        xg_w, xg_b, hg_w, hg_b, att, histbf, hfin);
  }
  final_kernel<<<dim3(B_), dim3(256), 0, stream>>>(targets, hfin, ln2_w, ln2_b, out);
}